// Round 6
// baseline (3272.097 us; speedup 1.0000x reference)
//
#include <hip/hip_runtime.h>
#include <math.h>

// LSTM persistent kernel, R6: TWO batch elements per block, 1024 threads.
// Half hb=tid>>9 owns batch 2*blockIdx+hb; within a half, quad owns
// h-element e=(tid>>2)&127; lane q=tid&3 holds gate rows e+{0,128,256,384}
// restricted to k-chunk [32q,32q+32), matvec via v_dot2_f32_f16.
//
// R6 rationale: R5 spent ~300 cy/step in a serial tail (barrier -> ds_read
// -> DPP reduce -> exp/rcp chain -> c update) that ALL waves wait through,
// with only 2 waves/SIMD of same-phase work. Co-locating 2 independent
// chains per block executes that tail once (lane-parallel across batches)
// and doubles dot-issue per SIMD (4 waves/SIMD) -> tail+barrier amortized
// over 2 chains: ~525 cy/chain vs 1135 measured in R5.
constexpr int Hdim = 128;
constexpr int TMAX = 4096;
constexpr int REPH = 136;  // f16 replica stride: conflict-free stagger (R5: 0 conflicts)

typedef _Float16 v2h __attribute__((ext_vector_type(2)));

template <int CTRL>
__device__ __forceinline__ float dppf(float v) {
  return __int_as_float(
      __builtin_amdgcn_update_dpp(0, __float_as_int(v), CTRL, 0xF, 0xF, true));
}

#if __has_builtin(__builtin_amdgcn_exp2f)
__device__ __forceinline__ float exp2_fast(float x) {
  return __builtin_amdgcn_exp2f(x);
}
#else
__device__ __forceinline__ float exp2_fast(float x) {
  return __expf(x * 0.6931471805599453f);
}
#endif

__global__ __launch_bounds__(1024) void lstm_persist(
    const float* __restrict__ data, const float* __restrict__ h0,
    const float* __restrict__ c0, const float* __restrict__ W_ih,
    const float* __restrict__ W_hh, const float* __restrict__ b_ih,
    const float* __restrict__ b_hh, const float* __restrict__ W_out,
    const float* __restrict__ b_out, float* __restrict__ out, int T) {
  __shared__ __align__(16) float xs[2][TMAX];
  __shared__ __align__(16) _Float16 hrep[2][2][4 * REPH];

  const int tid = threadIdx.x;
  const int hb = tid >> 9;         // which batch half of the block
  const int tl = tid & 511;        // thread index within half
  const int q = tid & 3;
  const int e = (tid >> 2) & 127;
  const int b = blockIdx.x * 2 + hb;

  // Stage this half's input row (coalesced float4, 512 threads per row).
  {
    const float4* src = (const float4*)(data + (size_t)b * T);
    float4* dst = (float4*)xs[hb];
    for (int i = tl; i < T / 4; i += 512) dst[i] = src[i];
  }

  constexpr float L2E = 1.44269504088896f;

  // Weights: 4 gate rows x 32 k = 64 packed f16 pairs, pre-scaled by Mk(r).
  // Same rows for both halves (depends only on e,q).
  v2h w[4][16];
#pragma unroll
  for (int r = 0; r < 4; ++r) {
    const float Mr = (r == 2) ? 2.0f * L2E : -L2E;
    const float* wr = W_hh + (size_t)(e + 128 * r) * Hdim + 32 * q;
#pragma unroll
    for (int j = 0; j < 8; ++j) {
      float4 v = ((const float4*)wr)[j];
      w[r][2 * j + 0] = v2h{(_Float16)(Mr * v.x), (_Float16)(Mr * v.y)};
      w[r][2 * j + 1] = v2h{(_Float16)(Mr * v.z), (_Float16)(Mr * v.w)};
    }
  }

  // Lane-constant activation params for MY gate (q: 0=i,1=f,2=g,3=o).
  const int row = e + 128 * q;
  const float MkL = (q == 2) ? 2.0f * L2E : -L2E;
  const float wihL = MkL * W_ih[row];
  const float bsL = MkL * (b_ih[row] + b_hh[row]);
  const float As = (q == 2) ? -2.0f : 1.0f;
  const float Bs = (q == 2) ? 1.0f : 0.0f;
  const bool qb0 = (q & 1) != 0;
  const bool qb1 = (q & 2) != 0;

  float c = c0[(size_t)b * Hdim + e];
  if (q == 0) {
    const _Float16 hh = (_Float16)h0[(size_t)b * Hdim + e];
    hrep[0][hb][0 * REPH + e] = hh;
    hrep[0][hb][1 * REPH + e] = hh;
    hrep[0][hb][2 * REPH + e] = hh;
    hrep[0][hb][3 * REPH + e] = hh;
  }
  __syncthreads();

  const float* xrow = xs[hb];
  for (int t0 = 0; t0 < T; t0 += 4) {
    const float4 xv = *(const float4*)&xrow[t0];
    const float xts[4] = {xv.x, xv.y, xv.z, xv.w};
#pragma unroll
    for (int u = 0; u < 4; ++u) {
      const int t = t0 + u;
      // My 32-half chunk of h (4x ds_read_b128, conflict-free stagger).
      const v2h* hp = (const v2h*)(&hrep[t & 1][hb][q * REPH + 32 * q]);
      v2h h2[16];
#pragma unroll
      for (int j = 0; j < 16; ++j) h2[j] = hp[j];

      float a0 = 0.f, a1 = 0.f, a2 = 0.f, a3 = 0.f;
#pragma unroll
      for (int j = 0; j < 16; ++j) {
        a0 = __builtin_amdgcn_fdot2(w[0][j], h2[j], a0, false);
        a1 = __builtin_amdgcn_fdot2(w[1][j], h2[j], a1, false);
        a2 = __builtin_amdgcn_fdot2(w[2][j], h2[j], a2, false);
        a3 = __builtin_amdgcn_fdot2(w[3][j], h2[j], a3, false);
      }

      // 2-stage DPP reduce-scatter: lane q ends with gate q's full sum.
      float x01 = qb0 ? a1 : a0;
      float y01 = qb0 ? a0 : a1;
      x01 += dppf<0xB1>(y01);
      float x23 = qb0 ? a3 : a2;
      float y23 = qb0 ? a2 : a3;
      x23 += dppf<0xB1>(y23);
      float z = qb1 ? x23 : x01;
      float zz = qb1 ? x01 : x23;
      z += dppf<0x4E>(zz);

      // Activation for my own gate (pre already scaled by Mk).
      const float pre = fmaf(xts[u], wihL, bsL) + z;
      const float y =
          fmaf(As, __builtin_amdgcn_rcpf(1.0f + exp2_fast(pre)), Bs);

      // Quad broadcast: gather i,f,g,o into every lane.
      const float yi = dppf<0x00>(y);
      const float yf = dppf<0x55>(y);
      const float yg = dppf<0xAA>(y);
      const float yo = dppf<0xFF>(y);

      c = fmaf(yf, c, yi * yg);
      const float th = fmaf(
          -2.0f, __builtin_amdgcn_rcpf(1.0f + exp2_fast(c * (2.0f * L2E))),
          1.0f);
      const float h = yo * th;

      hrep[(t + 1) & 1][hb][q * REPH + e] = (_Float16)h;
      __syncthreads();
    }
  }

  // Final linear: out[b] = h_T . W_out + b_out (lane 0..63 of each half's
  // first wave; thread 512 is wave 8 lane 0, so shfl width 64 stays in-wave).
  if (tl < 64) {
    const _Float16* hf = &hrep[T & 1][hb][0];
    float sum =
        (float)hf[tl] * W_out[tl] + (float)hf[tl + 64] * W_out[tl + 64];
#pragma unroll
    for (int off = 32; off > 0; off >>= 1) sum += __shfl_down(sum, off, 64);
    if (tl == 0) out[b] = sum + b_out[0];
  }
}

extern "C" void kernel_launch(void* const* d_in, const int* in_sizes, int n_in,
                              void* d_out, int out_size, void* d_ws,
                              size_t ws_size, hipStream_t stream) {
  const float* data = (const float*)d_in[0];
  const float* h0 = (const float*)d_in[1];
  const float* c0 = (const float*)d_in[2];
  const float* W_ih = (const float*)d_in[3];
  const float* W_hh = (const float*)d_in[4];
  const float* b_ih = (const float*)d_in[5];
  const float* b_hh = (const float*)d_in[6];
  const float* W_out = (const float*)d_in[7];
  const float* b_out = (const float*)d_in[8];
  float* out = (float*)d_out;

  const int B = in_sizes[1] / Hdim;  // 64
  const int T = in_sizes[0] / B;     // 4096

  lstm_persist<<<B / 2, 1024, 0, stream>>>(data, h0, c0, W_ih, W_hh, b_ih,
                                           b_hh, W_out, b_out, out, T);
}

// Round 7
// 3268.273 us; speedup vs baseline: 1.0012x; 1.0012x over previous
//
#include <hip/hip_runtime.h>
#include <math.h>

// LSTM persistent kernel, R7: TWO batch elements per block, 1024 threads,
// waves_per_eu(4,4). R6's co-location was right but the compiler targeted
// 2 workgroups/CU (8 waves/SIMD, 64-VGPR budget) and spilled the ~100-reg
// working set to SCRATCH (fdot2 VOP3P can't source AGPRs) -> 2.3 GB HBM
// writes/dispatch, 3272us. Pinning 4 waves/EU restores the 128-VGPR budget;
// everything fits, zero spill, one block/CU.
//
// Layout: half hb=tid>>9 owns batch 2*blockIdx+hb; quad owns h-element
// e=(tid>>2)&127; lane q=tid&3 holds gate rows e+{0,128,256,384} on k-chunk
// [32q,32q+32); matvec via v_dot2_f32_f16 (2 MAC/lane/instr, full VALU rate).
// Serial tail (DPP reduce-scatter -> exp2/rcp activation -> c update) runs
// once, lane-parallel across both chains.
constexpr int Hdim = 128;
constexpr int TMAX = 4096;
constexpr int REPH = 136;  // f16 replica stride: conflict-free stagger

typedef _Float16 v2h __attribute__((ext_vector_type(2)));

template <int CTRL>
__device__ __forceinline__ float dppf(float v) {
  return __int_as_float(
      __builtin_amdgcn_update_dpp(0, __float_as_int(v), CTRL, 0xF, 0xF, true));
}

#if __has_builtin(__builtin_amdgcn_exp2f)
__device__ __forceinline__ float exp2_fast(float x) {
  return __builtin_amdgcn_exp2f(x);
}
#else
__device__ __forceinline__ float exp2_fast(float x) {
  return __expf(x * 0.6931471805599453f);
}
#endif

__global__ __launch_bounds__(1024)
__attribute__((amdgpu_waves_per_eu(4, 4))) void lstm_persist(
    const float* __restrict__ data, const float* __restrict__ h0,
    const float* __restrict__ c0, const float* __restrict__ W_ih,
    const float* __restrict__ W_hh, const float* __restrict__ b_ih,
    const float* __restrict__ b_hh, const float* __restrict__ W_out,
    const float* __restrict__ b_out, float* __restrict__ out, int T) {
  __shared__ __align__(16) float xs[2][TMAX];
  __shared__ __align__(16) _Float16 hrep[2][2][4 * REPH];

  const int tid = threadIdx.x;
  const int hb = tid >> 9;   // which batch half of the block
  const int tl = tid & 511;  // thread index within half
  const int q = tid & 3;
  const int e = (tid >> 2) & 127;
  const int b = blockIdx.x * 2 + hb;

  // Stage this half's input row (coalesced float4, 512 threads per row).
  {
    const float4* src = (const float4*)(data + (size_t)b * T);
    float4* dst = (float4*)xs[hb];
    for (int i = tl; i < T / 4; i += 512) dst[i] = src[i];
  }

  constexpr float L2E = 1.44269504088896f;

  // Weights: 4 gate rows x 32 k = 64 packed f16 pairs, pre-scaled by Mk(r).
  // Same rows for both halves (depends only on e,q).
  v2h w[4][16];
#pragma unroll
  for (int r = 0; r < 4; ++r) {
    const float Mr = (r == 2) ? 2.0f * L2E : -L2E;
    const float* wr = W_hh + (size_t)(e + 128 * r) * Hdim + 32 * q;
#pragma unroll
    for (int j = 0; j < 8; ++j) {
      float4 v = ((const float4*)wr)[j];
      w[r][2 * j + 0] = v2h{(_Float16)(Mr * v.x), (_Float16)(Mr * v.y)};
      w[r][2 * j + 1] = v2h{(_Float16)(Mr * v.z), (_Float16)(Mr * v.w)};
    }
  }

  // Lane-constant activation params for MY gate (q: 0=i,1=f,2=g,3=o).
  const int row = e + 128 * q;
  const float MkL = (q == 2) ? 2.0f * L2E : -L2E;
  const float wihL = MkL * W_ih[row];
  const float bsL = MkL * (b_ih[row] + b_hh[row]);
  const float As = (q == 2) ? -2.0f : 1.0f;
  const float Bs = (q == 2) ? 1.0f : 0.0f;
  const bool qb0 = (q & 1) != 0;
  const bool qb1 = (q & 2) != 0;

  float c = c0[(size_t)b * Hdim + e];
  if (q == 0) {
    const _Float16 hh = (_Float16)h0[(size_t)b * Hdim + e];
    hrep[0][hb][0 * REPH + e] = hh;
    hrep[0][hb][1 * REPH + e] = hh;
    hrep[0][hb][2 * REPH + e] = hh;
    hrep[0][hb][3 * REPH + e] = hh;
  }
  __syncthreads();

  const float* xrow = xs[hb];
  for (int t0 = 0; t0 < T; t0 += 4) {
    const float4 xv = *(const float4*)&xrow[t0];
    const float xts[4] = {xv.x, xv.y, xv.z, xv.w};
#pragma unroll
    for (int u = 0; u < 4; ++u) {
      const int t = t0 + u;
      // My 32-half chunk of h (4x ds_read_b128, conflict-free stagger).
      const v2h* hp = (const v2h*)(&hrep[t & 1][hb][q * REPH + 32 * q]);
      v2h h2[16];
#pragma unroll
      for (int j = 0; j < 16; ++j) h2[j] = hp[j];

      float a0 = 0.f, a1 = 0.f, a2 = 0.f, a3 = 0.f;
#pragma unroll
      for (int j = 0; j < 16; ++j) {
        a0 = __builtin_amdgcn_fdot2(w[0][j], h2[j], a0, false);
        a1 = __builtin_amdgcn_fdot2(w[1][j], h2[j], a1, false);
        a2 = __builtin_amdgcn_fdot2(w[2][j], h2[j], a2, false);
        a3 = __builtin_amdgcn_fdot2(w[3][j], h2[j], a3, false);
      }

      // 2-stage DPP reduce-scatter: lane q ends with gate q's full sum.
      float x01 = qb0 ? a1 : a0;
      float y01 = qb0 ? a0 : a1;
      x01 += dppf<0xB1>(y01);
      float x23 = qb0 ? a3 : a2;
      float y23 = qb0 ? a2 : a3;
      x23 += dppf<0xB1>(y23);
      float z = qb1 ? x23 : x01;
      float zz = qb1 ? x01 : x23;
      z += dppf<0x4E>(zz);

      // Activation for my own gate (pre already scaled by Mk).
      const float pre = fmaf(xts[u], wihL, bsL) + z;
      const float y =
          fmaf(As, __builtin_amdgcn_rcpf(1.0f + exp2_fast(pre)), Bs);

      // Quad broadcast: gather i,f,g,o into every lane.
      const float yi = dppf<0x00>(y);
      const float yf = dppf<0x55>(y);
      const float yg = dppf<0xAA>(y);
      const float yo = dppf<0xFF>(y);

      c = fmaf(yf, c, yi * yg);
      const float th = fmaf(
          -2.0f, __builtin_amdgcn_rcpf(1.0f + exp2_fast(c * (2.0f * L2E))),
          1.0f);
      const float h = yo * th;

      hrep[(t + 1) & 1][hb][q * REPH + e] = (_Float16)h;
      __syncthreads();
    }
  }

  // Final linear: out[b] = h_T . W_out + b_out (lanes 0..63 of each half's
  // first wave; shfl width 64 stays in-wave).
  if (tl < 64) {
    const _Float16* hf = &hrep[T & 1][hb][0];
    float sum =
        (float)hf[tl] * W_out[tl] + (float)hf[tl + 64] * W_out[tl + 64];
#pragma unroll
    for (int off = 32; off > 0; off >>= 1) sum += __shfl_down(sum, off, 64);
    if (tl == 0) out[b] = sum + b_out[0];
  }
}

extern "C" void kernel_launch(void* const* d_in, const int* in_sizes, int n_in,
                              void* d_out, int out_size, void* d_ws,
                              size_t ws_size, hipStream_t stream) {
  const float* data = (const float*)d_in[0];
  const float* h0 = (const float*)d_in[1];
  const float* c0 = (const float*)d_in[2];
  const float* W_ih = (const float*)d_in[3];
  const float* W_hh = (const float*)d_in[4];
  const float* b_ih = (const float*)d_in[5];
  const float* b_hh = (const float*)d_in[6];
  const float* W_out = (const float*)d_in[7];
  const float* b_out = (const float*)d_in[8];
  float* out = (float*)d_out;

  const int B = in_sizes[1] / Hdim;  // 64
  const int T = in_sizes[0] / B;     // 4096

  lstm_persist<<<B / 2, 1024, 0, stream>>>(data, h0, c0, W_ih, W_hh, b_ih,
                                           b_hh, W_out, b_out, out, T);
}

// Round 8
// 1936.718 us; speedup vs baseline: 1.6895x; 1.6875x over previous
//
#include <hip/hip_runtime.h>
#include <math.h>

// LSTM persistent kernel, R8: one block per batch element, 512 threads.
// Structure identical to R5 (quad owns h-element e=tid>>2; lane q=tid&3
// holds gate rows e+{0,128,256,384} on k-chunk [32q,32q+32); matvec via
// v_dot2_f32_f16; DPP reduce-scatter; exp2/rcp activations).
//
// R8 change: LDS padded to 84 KB. Occupancy hints (launch_bounds 2nd arg,
// waves_per_eu) were ignored in R1/R2/R7 -- the allocator always budgets
// for 2 workgroups/CU (128 regs/wave at 512 thr), parking the 64 weight
// v2h regs in AGPRs and paying ~300 cy/step of v_accvgpr_read (R5: 816 cy
// measured VALU issue vs ~450 static). LDS > 80 KB is a PHYSICAL 1-WG/CU
// constraint the budget calc cannot ignore -> 2 waves/SIMD -> 256-reg
// budget -> weights fully arch-resident.
constexpr int Hdim = 128;
constexpr int TMAX = 4096;
constexpr int REPH = 136;  // f16 replica stride: conflict-free stagger

typedef _Float16 v2h __attribute__((ext_vector_type(2)));

template <int CTRL>
__device__ __forceinline__ float dppf(float v) {
  return __int_as_float(
      __builtin_amdgcn_update_dpp(0, __float_as_int(v), CTRL, 0xF, 0xF, true));
}

#if __has_builtin(__builtin_amdgcn_exp2f)
__device__ __forceinline__ float exp2_fast(float x) {
  return __builtin_amdgcn_exp2f(x);
}
#else
__device__ __forceinline__ float exp2_fast(float x) {
  return __expf(x * 0.6931471805599453f);
}
#endif

__global__ __launch_bounds__(512) void lstm_persist(
    const float* __restrict__ data, const float* __restrict__ h0,
    const float* __restrict__ c0, const float* __restrict__ W_ih,
    const float* __restrict__ W_hh, const float* __restrict__ b_ih,
    const float* __restrict__ b_hh, const float* __restrict__ W_out,
    const float* __restrict__ b_out, float* __restrict__ out, int T) {
  __shared__ __align__(16) float xs[TMAX];
  __shared__ __align__(16) _Float16 hrep[2][4 * REPH];
  // Occupancy clamp: total static LDS = 16384 + 2176 + 67456 = 86016 B
  // (84 KB) > 81920 B -> at most ONE workgroup per CU -> 2 waves/SIMD ->
  // 256-VGPR/wave budget. Never touched at runtime (T==4096).
  __shared__ float pad[16864];

  const int b = blockIdx.x;
  const int tid = threadIdx.x;
  const int q = tid & 3;
  const int e = tid >> 2;

  if (T == 0) {  // never true; keeps pad alive against elimination
    ((volatile float*)pad)[tid] = 1.0f;
    out[0] = ((volatile float*)pad)[tid ^ 1];
  }

  // Stage input row (coalesced float4).
  {
    const float4* src = (const float4*)(data + (size_t)b * T);
    float4* dst = (float4*)xs;
    for (int i = tid; i < T / 4; i += 512) dst[i] = src[i];
  }

  constexpr float L2E = 1.44269504088896f;

  // Weights: 4 gate rows x 32 k = 64 packed f16 pairs, pre-scaled by Mk(r).
  v2h w[4][16];
#pragma unroll
  for (int r = 0; r < 4; ++r) {
    const float Mr = (r == 2) ? 2.0f * L2E : -L2E;
    const float* wr = W_hh + (size_t)(e + 128 * r) * Hdim + 32 * q;
#pragma unroll
    for (int j = 0; j < 8; ++j) {
      float4 v = ((const float4*)wr)[j];
      w[r][2 * j + 0] = v2h{(_Float16)(Mr * v.x), (_Float16)(Mr * v.y)};
      w[r][2 * j + 1] = v2h{(_Float16)(Mr * v.z), (_Float16)(Mr * v.w)};
    }
  }

  // Lane-constant activation params for MY gate (q: 0=i,1=f,2=g,3=o).
  const int row = e + 128 * q;
  const float MkL = (q == 2) ? 2.0f * L2E : -L2E;
  const float wihL = MkL * W_ih[row];
  const float bsL = MkL * (b_ih[row] + b_hh[row]);
  const float As = (q == 2) ? -2.0f : 1.0f;
  const float Bs = (q == 2) ? 1.0f : 0.0f;
  const bool qb0 = (q & 1) != 0;
  const bool qb1 = (q & 2) != 0;

  float c = c0[(size_t)b * Hdim + e];
  if (q == 0) {
    const _Float16 hh = (_Float16)h0[(size_t)b * Hdim + e];
    hrep[0][0 * REPH + e] = hh;
    hrep[0][1 * REPH + e] = hh;
    hrep[0][2 * REPH + e] = hh;
    hrep[0][3 * REPH + e] = hh;
  }
  __syncthreads();

  for (int t0 = 0; t0 < T; t0 += 4) {
    const float4 xv = *(const float4*)&xs[t0];  // broadcast, off critical path
    const float xts[4] = {xv.x, xv.y, xv.z, xv.w};
#pragma unroll
    for (int u = 0; u < 4; ++u) {
      const int t = t0 + u;
      // My 32-half chunk of h (4x ds_read_b128, conflict-free stagger).
      const v2h* hp = (const v2h*)(&hrep[t & 1][q * REPH + 32 * q]);
      v2h h2[16];
#pragma unroll
      for (int j = 0; j < 16; ++j) h2[j] = hp[j];

      float a0 = 0.f, a1 = 0.f, a2 = 0.f, a3 = 0.f;
#pragma unroll
      for (int j = 0; j < 16; ++j) {
        a0 = __builtin_amdgcn_fdot2(w[0][j], h2[j], a0, false);
        a1 = __builtin_amdgcn_fdot2(w[1][j], h2[j], a1, false);
        a2 = __builtin_amdgcn_fdot2(w[2][j], h2[j], a2, false);
        a3 = __builtin_amdgcn_fdot2(w[3][j], h2[j], a3, false);
      }

      // 2-stage DPP reduce-scatter: lane q ends with gate q's full sum.
      float x01 = qb0 ? a1 : a0;
      float y01 = qb0 ? a0 : a1;
      x01 += dppf<0xB1>(y01);
      float x23 = qb0 ? a3 : a2;
      float y23 = qb0 ? a2 : a3;
      x23 += dppf<0xB1>(y23);
      float z = qb1 ? x23 : x01;
      float zz = qb1 ? x01 : x23;
      z += dppf<0x4E>(zz);

      // Activation for my own gate (pre already scaled by Mk).
      const float pre = fmaf(xts[u], wihL, bsL) + z;
      const float y =
          fmaf(As, __builtin_amdgcn_rcpf(1.0f + exp2_fast(pre)), Bs);

      // Quad broadcast: gather i,f,g,o into every lane.
      const float yi = dppf<0x00>(y);
      const float yf = dppf<0x55>(y);
      const float yg = dppf<0xAA>(y);
      const float yo = dppf<0xFF>(y);

      c = fmaf(yf, c, yi * yg);
      const float th = fmaf(
          -2.0f, __builtin_amdgcn_rcpf(1.0f + exp2_fast(c * (2.0f * L2E))),
          1.0f);
      const float h = yo * th;

      hrep[(t + 1) & 1][q * REPH + e] = (_Float16)h;
      __syncthreads();
    }
  }

  // Final linear: out[b] = h_T . W_out + b_out (wave 0, replica 0).
  if (tid < 64) {
    const _Float16* hf = &hrep[T & 1][0];
    float sum =
        (float)hf[tid] * W_out[tid] + (float)hf[tid + 64] * W_out[tid + 64];
#pragma unroll
    for (int off = 32; off > 0; off >>= 1) sum += __shfl_down(sum, off, 64);
    if (tid == 0) out[b] = sum + b_out[0];
  }
}

extern "C" void kernel_launch(void* const* d_in, const int* in_sizes, int n_in,
                              void* d_out, int out_size, void* d_ws,
                              size_t ws_size, hipStream_t stream) {
  const float* data = (const float*)d_in[0];
  const float* h0 = (const float*)d_in[1];
  const float* c0 = (const float*)d_in[2];
  const float* W_ih = (const float*)d_in[3];
  const float* W_hh = (const float*)d_in[4];
  const float* b_ih = (const float*)d_in[5];
  const float* b_hh = (const float*)d_in[6];
  const float* W_out = (const float*)d_in[7];
  const float* b_out = (const float*)d_in[8];
  float* out = (float*)d_out;

  const int B = in_sizes[1] / Hdim;  // 64
  const int T = in_sizes[0] / B;     // 4096

  lstm_persist<<<B, 512, 0, stream>>>(data, h0, c0, W_ih, W_hh, b_ih, b_hh,
                                      W_out, b_out, out, T);
}